// Round 3
// baseline (1114.399 us; speedup 1.0000x reference)
//
#include <hip/hip_runtime.h>

// ---------------------------------------------------------------------------
// Round 8: B direct-from-global (sB deleted).
// Round-7 accounting showed the LDS pipe ~81% busy (reads 249K + stores 76K +
// conflicts 51K cycles/CU vs MFMA 201K): the kernel was LDS-pipe-bound, not
// MFMA-bound. B fragments are now read straight from the repacked weight
// tensor in global memory (L2-resident panel, each 16-lane phase reads 256B
// contiguous), double-buffered in registers one tap ahead (bfa/bfb, parity
// made static by unrolling cb-PAIRS — CB is even for all layers). This
// removes all sB reads+writes from the LDS pipe (-~200K cyc/CU), cuts
// barriers 6/cb -> 2/cb (9-tap inner loop is barrier-free), and shrinks LDS
// to the A halo only (~16-21KB).
// ---------------------------------------------------------------------------

typedef __attribute__((ext_vector_type(8))) short short8;
typedef __attribute__((ext_vector_type(4))) float f32x4;

__device__ __forceinline__ float b2f(ushort u) {
    return __uint_as_float(((unsigned)u) << 16);
}
__device__ __forceinline__ ushort f2b(float f) {   // round-to-nearest-even
    unsigned x = __float_as_uint(f);
    x += 0x7FFFu + ((x >> 16) & 1u);
    return (ushort)(x >> 16);
}
__device__ __forceinline__ ushort bmax(ushort a, ushort b) {
    return b2f(a) > b2f(b) ? a : b;
}

// ---- repack weights [co][ci][t] f32 -> [t][cb][q][co][ci8] bf16 ------------
// (q = which 8-channel group of the 32-channel block; matches the MFMA
//  B-fragment quad so each 16-lane phase reads 256B contiguous from global.)
__global__ __launch_bounds__(256)
void repack_w(const float* __restrict__ w, ushort* __restrict__ wp, int Cin, int Cout)
{
    int n = Cout * Cin * 9;
    int i = blockIdx.x * 256 + threadIdx.x;
    if (i >= n) return;
    int CBl = Cin / 32;
    int c8   = i & 7;
    int co   = (i >> 3) % Cout;
    int rest = (i >> 3) / Cout;      // = (t*CBl + cb)*4 + q
    int q    = rest & 3;
    int cbt  = rest >> 2;
    int cb   = cbt % CBl;
    int t    = cbt / CBl;
    int ci   = cb * 32 + q * 8 + c8;
    wp[i] = f2b(w[((size_t)co * Cin + ci) * 9 + t]);
}

// ------------- L1: 3->64 direct conv, fp32 NCHW in -> bf16 NHWC out ---------
__global__ __launch_bounds__(256)
void l1_conv(const float* __restrict__ in, const float* __restrict__ w,
             const float* __restrict__ bias, ushort* __restrict__ out)
{
    const int H = 384, W = 384;
    __shared__ float s[3][18][18];
    const int tid = threadIdx.x;
    const int tilesX = W / 16;
    const int x0 = (blockIdx.x % tilesX) * 16;
    const int y0 = (blockIdx.x / tilesX) * 16;
    const int b  = blockIdx.z;

    for (int i = tid; i < 3 * 18 * 18; i += 256) {
        int ci = i / (18 * 18);
        int r  = i % (18 * 18);
        int iy = r / 18, ix = r % 18;
        int gy = y0 - 1 + iy, gx = x0 - 1 + ix;
        float v = 0.f;
        if ((unsigned)gy < (unsigned)H && (unsigned)gx < (unsigned)W)
            v = in[((size_t)(b * 3 + ci) * H + gy) * W + gx];
        s[ci][iy][ix] = v;
    }
    __syncthreads();

    const int tx = tid & 15, ty = tid >> 4;
    float iv[3][3][3];
    #pragma unroll
    for (int ci = 0; ci < 3; ++ci)
        #pragma unroll
        for (int ky = 0; ky < 3; ++ky)
            #pragma unroll
            for (int kx = 0; kx < 3; ++kx)
                iv[ci][ky][kx] = s[ci][ty + ky][tx + kx];

    size_t pix = ((size_t)(b * H + y0 + ty) * W + x0 + tx);
    #pragma unroll
    for (int c4 = 0; c4 < 4; ++c4) {
        __align__(16) ushort ob[16];
        #pragma unroll
        for (int co = 0; co < 16; ++co) {
            int coG = c4 * 16 + co;
            float a = bias[coG];
            #pragma unroll
            for (int ci = 0; ci < 3; ++ci)
                #pragma unroll
                for (int ky = 0; ky < 3; ++ky)
                    #pragma unroll
                    for (int kx = 0; kx < 3; ++kx)
                        a = fmaf(w[((size_t)coG * 3 + ci) * 9 + ky * 3 + kx],
                                 iv[ci][ky][kx], a);
            a = a > 0.f ? a : 0.f;
            ob[co] = f2b(a);
        }
        *(short8*)&out[pix * 64 + c4 * 16]     = *(short8*)&ob[0];
        *(short8*)&out[pix * 64 + c4 * 16 + 8] = *(short8*)&ob[8];
    }
}

// ------------- 2x2 maxpool, bf16 NHWC ---------------------------------------
__global__ __launch_bounds__(256)
void maxpool_nhwc(const ushort* __restrict__ in, ushort* __restrict__ out,
                  int Ho, int Wo, int C)
{
    int n = 4 * Ho * Wo * (C / 8);
    int i = blockIdx.x * 256 + threadIdx.x;
    if (i >= n) return;
    int c8 = i % (C / 8);
    int pi = i / (C / 8);
    int x = pi % Wo, y = (pi / Wo) % Ho, b = pi / (Wo * Ho);
    int Hi = Ho * 2, Wi = Wo * 2;
    const ushort* p = in + ((size_t)(b * Hi + 2 * y) * Wi + 2 * x) * C + c8 * 8;
    short8 v00 = *(const short8*)p;
    short8 v01 = *(const short8*)(p + C);
    short8 v10 = *(const short8*)(p + (size_t)Wi * C);
    short8 v11 = *(const short8*)(p + (size_t)Wi * C + C);
    short8 o;
    #pragma unroll
    for (int j = 0; j < 8; ++j)
        o[j] = (short)bmax(bmax((ushort)v00[j], (ushort)v01[j]),
                           bmax((ushort)v10[j], (ushort)v11[j]));
    *(short8*)(out + (size_t)i * 8) = o;
}

// ------------- irregular pool (mask-gated 2x2 max, replicated), NHWC --------
__global__ __launch_bounds__(256)
void irpool_nhwc(const ushort* __restrict__ in, const int* __restrict__ mask,
                 ushort* __restrict__ out)
{
    const int C = 256, H = 96, Wd = 96;
    int n = 4 * H * Wd * (C / 8);
    int i = blockIdx.x * 256 + threadIdx.x;
    if (i >= n) return;
    int c8 = i % (C / 8);
    int pi = i / (C / 8);
    int x = pi % Wd, y = (pi / Wd) % H, b = pi / (Wd * H);
    int m = mask[(b * 48 + (y >> 1)) * 48 + (x >> 1)];
    short8 o;
    if (m) {
        int y0 = y & ~1, x0 = x & ~1;
        const ushort* p = in + ((size_t)(b * H + y0) * Wd + x0) * C + c8 * 8;
        short8 v00 = *(const short8*)p;
        short8 v01 = *(const short8*)(p + C);
        short8 v10 = *(const short8*)(p + (size_t)Wd * C);
        short8 v11 = *(const short8*)(p + (size_t)Wd * C + C);
        #pragma unroll
        for (int j = 0; j < 8; ++j)
            o[j] = (short)bmax(bmax((ushort)v00[j], (ushort)v01[j]),
                               bmax((ushort)v10[j], (ushort)v11[j]));
    } else {
        o = *(const short8*)(in + (size_t)pi * C + c8 * 8);
    }
    *(short8*)(out + (size_t)pi * C + c8 * 8) = o;
}

// ------------- implicit-GEMM conv3x3, A in LDS, B direct-from-global --------
// Block = TRx16 output pixels, 256 threads = 4 waves, wave tile 64x64.
// A halo staged in LDS once per cb (register-prefetched one cb ahead);
// B fragments read straight from global (repacked, coalesced 256B/phase),
// register double-buffered one tap ahead. cb-loop unrolled in PAIRS so the
// bfa/bfb parity is compile-time static (CB is even for every layer).
// Barriers: 2 per cb, 9-tap MFMA section is barrier-free.
template<int TR, int BN, int CIN, int COUT, int H, int W, bool GCONV, bool FINAL>
__global__ __launch_bounds__(256)
void conv_mfma(const ushort* __restrict__ in, const ushort* __restrict__ wp,
               const float* __restrict__ bias, void* __restrict__ outv,
               const int* __restrict__ mask)
{
    constexpr int BM   = TR * 16;
    constexpr int CB   = CIN / 32;
    static_assert(CB % 2 == 0, "cb-pair unroll needs even CB");
    constexpr int HA   = GCONV ? 2 : 1;
    constexpr int CW   = 16 + 2 * HA;
    constexpr int CR   = TR + 2 * HA;
    constexpr int NCH  = CR * CW;            // A chunks (pixels) per cb
    constexpr int NCHP = NCH + 2;            // q-plane stride (de-alias stores)
    constexpr int WM   = BM / 64;
    constexpr int NSA  = NCH * 4;            // 16B units to stage for A
    constexpr int NSLA = (NSA + 255) / 256;

    // sA: [q][chunk] 16B units, plane stride NCHP. Fragment read:
    //   unit = quad*NCHP + chunk  -> 16B/lane linear per 16-lane phase.
    __shared__ __align__(16) ushort sA[4 * NCHP * 8];

    const int tid  = threadIdx.x;
    const int lane = tid & 63;
    const int wv   = tid >> 6;
    const int wm   = wv % WM;
    const int wn   = wv / WM;
    const int col  = lane & 15;
    const int quad = lane >> 4;

    const int tiles_x = W / 16, tiles_y = H / TR;
    int sp = blockIdx.x;
    const int b  = sp / (tiles_x * tiles_y);
    int rr = sp - b * tiles_x * tiles_y;
    const int ty = rr / tiles_x;
    const int tx = rr - ty * tiles_x;
    const int y0 = ty * TR, x0 = tx * 16;
    const int co0 = blockIdx.y * BN;

    int dA[4], aoff[4];
    #pragma unroll
    for (int mt = 0; mt < 4; ++mt) {
        dA[mt] = 1;
        if (GCONV) {
            int y = y0 + wm * 4 + mt, x = x0 + col;
            dA[mt] = mask[(b * (H / 2) + (y >> 1)) * (W / 2) + (x >> 1)] ? 2 : 1;
        }
        aoff[mt] = (HA + wm * 4 + mt) * CW + HA + col;
    }

    // per-lane base into repacked weights: [t][cb][q][co][ci8]
    const ushort* wbase = wp + ((size_t)quad * COUT + co0 + wn * 64 + col) * 8;

    short8 pA[NSLA];

    auto loadA = [&](int cb) {
        #pragma unroll
        for (int k = 0; k < NSLA; ++k) {
            int i = tid + k * 256;
            short8 v = {0, 0, 0, 0, 0, 0, 0, 0};
            if (NSA == NSLA * 256 || i < NSA) {
                int chunk = i >> 2, part = i & 3;     // coalesced: 64B / 4 lanes
                int yy = chunk / CW, xx = chunk - yy * CW;
                int gy = y0 - HA + yy, gx = x0 - HA + xx;
                if ((unsigned)gy < (unsigned)H && (unsigned)gx < (unsigned)W)
                    v = *(const short8*)(in + ((size_t)(b * H + gy) * W + gx) * CIN
                                         + cb * 32 + part * 8);
            }
            pA[k] = v;
        }
    };
    auto storeA = [&]() {
        #pragma unroll
        for (int k = 0; k < NSLA; ++k) {
            int i = tid + k * 256;
            if (NSA == NSLA * 256 || i < NSA) {
                int chunk = i >> 2, part = i & 3;
                *(short8*)&sA[(part * NCHP + chunk) * 8] = pA[k];
            }
        }
    };

    short8 bfa[4], bfb[4];
    auto loadBF = [&](int t, int cb, short8 (&dst)[4]) {
        size_t ofs = (size_t)(t * CB + cb) * 4 * COUT * 8;
        #pragma unroll
        for (int nt = 0; nt < 4; ++nt)
            dst[nt] = *(const short8*)(wbase + ofs + nt * 128);  // nt*16 co
    };

    f32x4 acc[4][4];
    #pragma unroll
    for (int i = 0; i < 4; ++i)
        #pragma unroll
        for (int j = 0; j < 4; ++j)
            acc[i][j] = (f32x4){0.f, 0.f, 0.f, 0.f};

    // prologue
    loadA(0);
    storeA();
    loadBF(0, 0, bfa);
    __syncthreads();

    for (int cb2 = 0; cb2 < CB; cb2 += 2) {
        loadA(cb2 + 1);                    // prefetch next cb's halo into regs
        #pragma unroll
        for (int g = 0; g < 18; ++g) {
            const int tt = (g >= 9) ? g - 9 : g;
            if (g == 9) {
                __syncthreads();           // all reads of sA(cb2) done
                storeA();                  // sA <- cb2+1
                __syncthreads();
                if (cb2 + 2 < CB) loadA(cb2 + 2);
            }
            // B prefetch for next tap (register double-buffer)
            {
                int gn = g + 1;
                int cbn = cb2 + (gn >= 9 ? 1 : 0);
                int tn  = (gn >= 9) ? gn - 9 : gn;
                if (gn == 18) { cbn = cb2 + 2; tn = 0; }
                if (cbn < CB) {
                    if ((g & 1) == 0) loadBF(tn, cbn, bfb);
                    else              loadBF(tn, cbn, bfa);
                }
            }
            const int ky = tt / 3 - 1, kx = tt % 3 - 1;
            short8 af[4];
            #pragma unroll
            for (int i = 0; i < 4; ++i) {
                int chunk = aoff[i] + dA[i] * (ky * CW + kx);
                af[i] = *(const short8*)&sA[(quad * NCHP + chunk) * 8];
            }
            #pragma unroll
            for (int mt = 0; mt < 4; ++mt)
                #pragma unroll
                for (int nt = 0; nt < 4; ++nt)
                    acc[mt][nt] = __builtin_amdgcn_mfma_f32_16x16x32_bf16(
                        af[mt], (g & 1) ? bfb[nt] : bfa[nt], acc[mt][nt], 0, 0, 0);
        }
        if (cb2 + 2 < CB) {
            __syncthreads();               // all reads of sA(cb2+1) done
            storeA();                      // sA <- cb2+2
            __syncthreads();
        }
    }

    // ---- epilogue ----
    if (!FINAL) {
        ushort* outp = (ushort*)outv;
        #pragma unroll
        for (int mt = 0; mt < 4; ++mt) {
            int y = y0 + wm * 4 + mt;
            #pragma unroll
            for (int nt = 0; nt < 4; ++nt) {
                int co = co0 + wn * 64 + nt * 16 + col;
                float bv = bias[co];
                #pragma unroll
                for (int r2 = 0; r2 < 4; ++r2) {
                    int x = x0 + quad * 4 + r2;
                    float vv = acc[mt][nt][r2] + bv;
                    vv = vv > 0.f ? vv : 0.f;
                    outp[((size_t)(b * H + y) * W + x) * COUT + co] = f2b(vv);
                }
            }
        }
    } else {
        float* outp = (float*)outv;   // fp32 NCHW direct to d_out
        #pragma unroll
        for (int mt = 0; mt < 4; ++mt) {
            int y = y0 + wm * 4 + mt;
            #pragma unroll
            for (int nt = 0; nt < 4; ++nt) {
                int co = co0 + wn * 64 + nt * 16 + col;
                float bv = bias[co];
                f32x4 vv;
                #pragma unroll
                for (int r2 = 0; r2 < 4; ++r2) {
                    float z = acc[mt][nt][r2] + bv;
                    vv[r2] = z > 0.f ? z : 0.f;
                }
                *(f32x4*)&outp[((size_t)(b * COUT + co) * H + y) * W + x0 + quad * 4] = vv;
            }
        }
    }
}

// ---------------------------------------------------------------------------
extern "C" void kernel_launch(void* const* d_in, const int* in_sizes, int n_in,
                              void* d_out, int out_size, void* d_ws, size_t ws_size,
                              hipStream_t stream)
{
    const float* x    = (const float*)d_in[0];
    const int*   mask = (const int*)d_in[1];
    const float* Wt[10];
    const float* bs[10];
    for (int i = 0; i < 10; ++i) {
        Wt[i] = (const float*)d_in[2 + 2 * i];
        bs[i] = (const float*)d_in[3 + 2 * i];
    }

    const size_t ACT = (size_t)4 * 384 * 384 * 64;   // ushorts
    ushort* A  = (ushort*)d_ws;
    ushort* Bb = A + ACT;
    ushort* wpbase = Bb + ACT;

    static const int cins[10]  = {3, 64, 64, 128, 128, 256, 256, 256, 512, 512};
    static const int couts[10] = {64, 64, 128, 128, 256, 256, 256, 512, 512, 512};
    ushort* wp[10];
    size_t wo = 0;
    for (int l = 1; l < 10; ++l) {
        wp[l] = wpbase + wo;
        wo += (size_t)couts[l] * cins[l] * 9;
    }
    for (int l = 1; l < 10; ++l) {
        int n = couts[l] * cins[l] * 9;
        repack_w<<<(n + 255) / 256, 256, 0, stream>>>(Wt[l], wp[l], cins[l], couts[l]);
    }

    // L1: fp32 NCHW -> bf16 NHWC
    l1_conv<<<dim3(24 * 24, 1, 4), 256, 0, stream>>>(x, Wt[0], bs[0], A);

    // L2: 64->64 @384 (tile 16x16, BN=64)
    conv_mfma<16, 64, 64, 64, 384, 384, false, false>
        <<<dim3(4 * 24 * 24, 1), 256, 0, stream>>>(A, wp[1], bs[1], Bb, nullptr);
    maxpool_nhwc<<<(4 * 192 * 192 * 8 + 255) / 256, 256, 0, stream>>>(Bb, A, 192, 192, 64);

    // L3: 64->128 @192 (tile 8x16, BN=128)
    conv_mfma<8, 128, 64, 128, 192, 192, false, false>
        <<<dim3(4 * 24 * 12, 1), 256, 0, stream>>>(A, wp[2], bs[2], Bb, nullptr);
    // L4: 128->128 @192
    conv_mfma<8, 128, 128, 128, 192, 192, false, false>
        <<<dim3(4 * 24 * 12, 1), 256, 0, stream>>>(Bb, wp[3], bs[3], A, nullptr);
    maxpool_nhwc<<<(4 * 96 * 96 * 16 + 255) / 256, 256, 0, stream>>>(A, Bb, 96, 96, 128);

    // L5: 128->256 @96
    conv_mfma<8, 128, 128, 256, 96, 96, false, false>
        <<<dim3(4 * 12 * 6, 2), 256, 0, stream>>>(Bb, wp[4], bs[4], A, nullptr);
    // L6: 256->256
    conv_mfma<8, 128, 256, 256, 96, 96, false, false>
        <<<dim3(4 * 12 * 6, 2), 256, 0, stream>>>(A, wp[5], bs[5], Bb, nullptr);
    // L7: 256->256
    conv_mfma<8, 128, 256, 256, 96, 96, false, false>
        <<<dim3(4 * 12 * 6, 2), 256, 0, stream>>>(Bb, wp[6], bs[6], A, nullptr);

    // irregular pool
    irpool_nhwc<<<(4 * 96 * 96 * 32 + 255) / 256, 256, 0, stream>>>(A, mask, Bb);

    // L8: gconv 256->512
    conv_mfma<8, 128, 256, 512, 96, 96, true, false>
        <<<dim3(4 * 12 * 6, 4), 256, 0, stream>>>(Bb, wp[7], bs[7], A, mask);
    // L9: gconv 512->512
    conv_mfma<8, 128, 512, 512, 96, 96, true, false>
        <<<dim3(4 * 12 * 6, 4), 256, 0, stream>>>(A, wp[8], bs[8], Bb, mask);
    // L10: gconv 512->512 -> fp32 NCHW d_out
    conv_mfma<8, 128, 512, 512, 96, 96, true, true>
        <<<dim3(4 * 12 * 6, 4), 256, 0, stream>>>(Bb, wp[9], bs[9], d_out, mask);

    (void)in_sizes; (void)n_in; (void)out_size; (void)ws_size;
}

// Round 4
// 1017.010 us; speedup vs baseline: 1.0958x; 1.0958x over previous
//
#include <hip/hip_runtime.h>

// ---------------------------------------------------------------------------
// Round 9: R7 inner loop (best: 957us) + persistent atomic-scheduled blocks.
// R8 post-mortem: B-direct-from-global regressed (229us vs 193) — 1-tap reg
// prefetch can't hide L2 latency; conflicts (1.302e7) proved to be all from
// sA's gconv divergence, not sB. Reverted to LDS-resident B.
// This round: L9/L10 launch 1152 blocks at ~4 resident/CU -> a 128-block
// second round runs at ~1/8 chip utilization (~11-20% tail). Each conv block
// now grabs tiles from a per-layer atomic counter (persistent), shrinking the
// tail to ~one tile. Inner loop untouched (clean A/B of the tail theory).
// ---------------------------------------------------------------------------

typedef __attribute__((ext_vector_type(8))) short short8;
typedef __attribute__((ext_vector_type(4))) float f32x4;

__device__ __forceinline__ float b2f(ushort u) {
    return __uint_as_float(((unsigned)u) << 16);
}
__device__ __forceinline__ ushort f2b(float f) {   // round-to-nearest-even
    unsigned x = __float_as_uint(f);
    x += 0x7FFFu + ((x >> 16) & 1u);
    return (ushort)(x >> 16);
}
__device__ __forceinline__ ushort bmax(ushort a, ushort b) {
    return b2f(a) > b2f(b) ? a : b;
}

__global__ void zero_counters(int* __restrict__ c) { c[threadIdx.x] = 0; }

// ---- repack weights [co][ci][t] f32 -> [t][cb][q][co][ci8] bf16 ------------
__global__ __launch_bounds__(256)
void repack_w(const float* __restrict__ w, ushort* __restrict__ wp, int Cin, int Cout)
{
    int n = Cout * Cin * 9;
    int i = blockIdx.x * 256 + threadIdx.x;
    if (i >= n) return;
    int CBl = Cin / 32;
    int c8   = i & 7;
    int co   = (i >> 3) % Cout;
    int rest = (i >> 3) / Cout;      // = (t*CBl + cb)*4 + q
    int q    = rest & 3;
    int cbt  = rest >> 2;
    int cb   = cbt % CBl;
    int t    = cbt / CBl;
    int ci   = cb * 32 + q * 8 + c8;
    wp[i] = f2b(w[((size_t)co * Cin + ci) * 9 + t]);
}

// ------------- L1: 3->64 direct conv, fp32 NCHW in -> bf16 NHWC out ---------
__global__ __launch_bounds__(256)
void l1_conv(const float* __restrict__ in, const float* __restrict__ w,
             const float* __restrict__ bias, ushort* __restrict__ out)
{
    const int H = 384, W = 384;
    __shared__ float s[3][18][18];
    const int tid = threadIdx.x;
    const int tilesX = W / 16;
    const int x0 = (blockIdx.x % tilesX) * 16;
    const int y0 = (blockIdx.x / tilesX) * 16;
    const int b  = blockIdx.z;

    for (int i = tid; i < 3 * 18 * 18; i += 256) {
        int ci = i / (18 * 18);
        int r  = i % (18 * 18);
        int iy = r / 18, ix = r % 18;
        int gy = y0 - 1 + iy, gx = x0 - 1 + ix;
        float v = 0.f;
        if ((unsigned)gy < (unsigned)H && (unsigned)gx < (unsigned)W)
            v = in[((size_t)(b * 3 + ci) * H + gy) * W + gx];
        s[ci][iy][ix] = v;
    }
    __syncthreads();

    const int tx = tid & 15, ty = tid >> 4;
    float iv[3][3][3];
    #pragma unroll
    for (int ci = 0; ci < 3; ++ci)
        #pragma unroll
        for (int ky = 0; ky < 3; ++ky)
            #pragma unroll
            for (int kx = 0; kx < 3; ++kx)
                iv[ci][ky][kx] = s[ci][ty + ky][tx + kx];

    size_t pix = ((size_t)(b * H + y0 + ty) * W + x0 + tx);
    #pragma unroll
    for (int c4 = 0; c4 < 4; ++c4) {
        __align__(16) ushort ob[16];
        #pragma unroll
        for (int co = 0; co < 16; ++co) {
            int coG = c4 * 16 + co;
            float a = bias[coG];
            #pragma unroll
            for (int ci = 0; ci < 3; ++ci)
                #pragma unroll
                for (int ky = 0; ky < 3; ++ky)
                    #pragma unroll
                    for (int kx = 0; kx < 3; ++kx)
                        a = fmaf(w[((size_t)coG * 3 + ci) * 9 + ky * 3 + kx],
                                 iv[ci][ky][kx], a);
            a = a > 0.f ? a : 0.f;
            ob[co] = f2b(a);
        }
        *(short8*)&out[pix * 64 + c4 * 16]     = *(short8*)&ob[0];
        *(short8*)&out[pix * 64 + c4 * 16 + 8] = *(short8*)&ob[8];
    }
}

// ------------- 2x2 maxpool, bf16 NHWC ---------------------------------------
__global__ __launch_bounds__(256)
void maxpool_nhwc(const ushort* __restrict__ in, ushort* __restrict__ out,
                  int Ho, int Wo, int C)
{
    int n = 4 * Ho * Wo * (C / 8);
    int i = blockIdx.x * 256 + threadIdx.x;
    if (i >= n) return;
    int c8 = i % (C / 8);
    int pi = i / (C / 8);
    int x = pi % Wo, y = (pi / Wo) % Ho, b = pi / (Wo * Ho);
    int Hi = Ho * 2, Wi = Wo * 2;
    const ushort* p = in + ((size_t)(b * Hi + 2 * y) * Wi + 2 * x) * C + c8 * 8;
    short8 v00 = *(const short8*)p;
    short8 v01 = *(const short8*)(p + C);
    short8 v10 = *(const short8*)(p + (size_t)Wi * C);
    short8 v11 = *(const short8*)(p + (size_t)Wi * C + C);
    short8 o;
    #pragma unroll
    for (int j = 0; j < 8; ++j)
        o[j] = (short)bmax(bmax((ushort)v00[j], (ushort)v01[j]),
                           bmax((ushort)v10[j], (ushort)v11[j]));
    *(short8*)(out + (size_t)i * 8) = o;
}

// ------------- irregular pool (mask-gated 2x2 max, replicated), NHWC --------
__global__ __launch_bounds__(256)
void irpool_nhwc(const ushort* __restrict__ in, const int* __restrict__ mask,
                 ushort* __restrict__ out)
{
    const int C = 256, H = 96, Wd = 96;
    int n = 4 * H * Wd * (C / 8);
    int i = blockIdx.x * 256 + threadIdx.x;
    if (i >= n) return;
    int c8 = i % (C / 8);
    int pi = i / (C / 8);
    int x = pi % Wd, y = (pi / Wd) % H, b = pi / (Wd * H);
    int m = mask[(b * 48 + (y >> 1)) * 48 + (x >> 1)];
    short8 o;
    if (m) {
        int y0 = y & ~1, x0 = x & ~1;
        const ushort* p = in + ((size_t)(b * H + y0) * Wd + x0) * C + c8 * 8;
        short8 v00 = *(const short8*)p;
        short8 v01 = *(const short8*)(p + C);
        short8 v10 = *(const short8*)(p + (size_t)Wd * C);
        short8 v11 = *(const short8*)(p + (size_t)Wd * C + C);
        #pragma unroll
        for (int j = 0; j < 8; ++j)
            o[j] = (short)bmax(bmax((ushort)v00[j], (ushort)v01[j]),
                               bmax((ushort)v10[j], (ushort)v11[j]));
    } else {
        o = *(const short8*)(in + (size_t)pi * C + c8 * 8);
    }
    *(short8*)(out + (size_t)pi * C + c8 * 8) = o;
}

// ------------- implicit-GEMM conv3x3, tap-row staged, bf16 MFMA -------------
// Persistent blocks: each block grabs tiles t = (pixel-tile, co-slab) from a
// per-layer atomic counter until exhausted. Inner loop is the R7 structure:
// A halo staged once per cb; B staged per tap-ROW with register prefetch of
// next row's B / next cb's A before the MFMA section. Conflict-free LDS
// layouts (sA q-plane-major stride NCH+2; sB [tap][q][co] wave-linear).
template<int TR, int BN, int CIN, int COUT, int H, int W, bool GCONV, bool FINAL>
__global__ __launch_bounds__(256)
void conv_mfma(const ushort* __restrict__ in, const ushort* __restrict__ wp,
               const float* __restrict__ bias, void* __restrict__ outv,
               const int* __restrict__ mask, int* __restrict__ counter)
{
    constexpr int BM   = TR * 16;
    constexpr int CB   = CIN / 32;
    constexpr int HA   = GCONV ? 2 : 1;
    constexpr int CW   = 16 + 2 * HA;
    constexpr int CR   = TR + 2 * HA;
    constexpr int NCH  = CR * CW;            // A chunks (pixels) per cb
    constexpr int NCHP = NCH + 2;            // q-plane stride (de-alias stores)
    constexpr int WM   = BM / 64;
    constexpr int NSA  = NCH * 4;            // 16B units to stage for A
    constexpr int NSLA = (NSA + 255) / 256;
    constexpr int NSB  = 12 * BN;            // 16B units per tap-row of B
    constexpr int NSLB = NSB / 256;
    static_assert(NSB % 256 == 0, "B staging must tile 256 threads");
    constexpr int NSP    = 4 * (H / TR) * (W / 16);   // pixel tiles
    constexpr int NSLAB  = COUT / BN;                 // co slabs
    constexpr int NTILES = NSP * NSLAB;

    __shared__ __align__(16) ushort sA[4 * NCHP * 8];
    __shared__ __align__(16) ushort sB[12 * BN * 8];
    __shared__ int s_tile;

    const int tid  = threadIdx.x;
    const int lane = tid & 63;
    const int wv   = tid >> 6;
    const int wm   = wv % WM;
    const int wn   = wv / WM;
    const int col  = lane & 15;
    const int quad = lane >> 4;
    const int tiles_x = W / 16, tiles_y = H / TR;

    while (true) {
        if (tid == 0) s_tile = atomicAdd(counter, 1);
        __syncthreads();                  // broadcast tile; also fences LDS
        const int t = s_tile;             //   reuse from the previous tile
        if (t >= NTILES) break;

        const int sp  = t % NSP;
        const int co0 = (t / NSP) * BN;
        const int b  = sp / (tiles_x * tiles_y);
        int rr = sp - b * tiles_x * tiles_y;
        const int ty = rr / tiles_x;
        const int tx = rr - ty * tiles_x;
        const int y0 = ty * TR, x0 = tx * 16;

        int dA[4], aoff[4];
        #pragma unroll
        for (int mt = 0; mt < 4; ++mt) {
            dA[mt] = 1;
            if (GCONV) {
                int y = y0 + wm * 4 + mt, x = x0 + col;
                dA[mt] = mask[(b * (H / 2) + (y >> 1)) * (W / 2) + (x >> 1)] ? 2 : 1;
            }
            aoff[mt] = (HA + wm * 4 + mt) * CW + HA + col;
        }

        short8 pA[NSLA];
        short8 pB[NSLB];

        auto loadA = [&](int cb) {
            #pragma unroll
            for (int k = 0; k < NSLA; ++k) {
                int i = tid + k * 256;
                short8 v = {0, 0, 0, 0, 0, 0, 0, 0};
                if (NSA == NSLA * 256 || i < NSA) {
                    int chunk = i >> 2, part = i & 3;  // coalesced: 64B / 4 lanes
                    int yy = chunk / CW, xx = chunk - yy * CW;
                    int gy = y0 - HA + yy, gx = x0 - HA + xx;
                    if ((unsigned)gy < (unsigned)H && (unsigned)gx < (unsigned)W)
                        v = *(const short8*)(in + ((size_t)(b * H + gy) * W + gx) * CIN
                                             + cb * 32 + part * 8);
                }
                pA[k] = v;
            }
        };
        auto storeA = [&]() {
            #pragma unroll
            for (int k = 0; k < NSLA; ++k) {
                int i = tid + k * 256;
                if (NSA == NSLA * 256 || i < NSA) {
                    int chunk = i >> 2, part = i & 3;
                    *(short8*)&sA[(part * NCHP + chunk) * 8] = pA[k];
                }
            }
        };
        auto loadB = [&](int s) {
            int cb = s / 3, row = s % 3;
            #pragma unroll
            for (int k = 0; k < NSLB; ++k) {
                int i = tid + k * 256;
                int co = i % BN;
                int rq = i / BN;                     // tl*4 + q
                const ushort* gp = wp
                    + (((size_t)(row * 3 + (rq >> 2)) * CB + cb) * 4 + (rq & 3))
                          * COUT * 8
                    + (size_t)(co0 + co) * 8;
                pB[k] = *(const short8*)gp;          // wave reads 1KB contiguous
            }
        };
        auto storeB = [&]() {
            #pragma unroll
            for (int k = 0; k < NSLB; ++k) {
                int i = tid + k * 256;
                *(short8*)&sB[(size_t)i * 8] = pB[k];  // wave-linear, 0 conflicts
            }
        };

        f32x4 acc[4][4];
        #pragma unroll
        for (int i = 0; i < 4; ++i)
            #pragma unroll
            for (int j = 0; j < 4; ++j)
                acc[i][j] = (f32x4){0.f, 0.f, 0.f, 0.f};

        // prologue
        loadA(0);
        loadB(0);
        storeA();
        storeB();
        __syncthreads();

        for (int s = 0; s < 3 * CB; ++s) {
            const int row  = s % 3;
            const bool last = (s == 3 * CB - 1);
            if (!last) {
                loadB(s + 1);                 // global prefetch, lands at storeB
                if (row == 2) loadA(s / 3 + 1);
            }
            const int ky = row - 1;
            #pragma unroll
            for (int j = 0; j < 3; ++j) {
                const int kx = j - 1;
                short8 af[4], bf4[4];
                #pragma unroll
                for (int i = 0; i < 4; ++i) {
                    int chunk = aoff[i] + dA[i] * (ky * CW + kx);
                    af[i]  = *(const short8*)&sA[(quad * NCHP + chunk) * 8];
                    bf4[i] = *(const short8*)&sB[((j * 4 + quad) * BN
                                                  + wn * 64 + i * 16 + col) * 8];
                }
                #pragma unroll
                for (int mt = 0; mt < 4; ++mt)
                    #pragma unroll
                    for (int nt = 0; nt < 4; ++nt)
                        acc[mt][nt] = __builtin_amdgcn_mfma_f32_16x16x32_bf16(
                            af[mt], bf4[nt], acc[mt][nt], 0, 0, 0);
            }
            if (!last) {
                __syncthreads();              // all reads of sA/sB done
                storeB();
                if (row == 2) storeA();
                __syncthreads();              // writes visible
            }
        }

        // ---- epilogue ----
        if (!FINAL) {
            ushort* outp = (ushort*)outv;
            #pragma unroll
            for (int mt = 0; mt < 4; ++mt) {
                int y = y0 + wm * 4 + mt;
                #pragma unroll
                for (int nt = 0; nt < 4; ++nt) {
                    int co = co0 + wn * 64 + nt * 16 + col;
                    float bv = bias[co];
                    #pragma unroll
                    for (int r2 = 0; r2 < 4; ++r2) {
                        int x = x0 + quad * 4 + r2;
                        float vv = acc[mt][nt][r2] + bv;
                        vv = vv > 0.f ? vv : 0.f;
                        outp[((size_t)(b * H + y) * W + x) * COUT + co] = f2b(vv);
                    }
                }
            }
        } else {
            float* outp = (float*)outv;   // fp32 NCHW direct to d_out
            #pragma unroll
            for (int mt = 0; mt < 4; ++mt) {
                int y = y0 + wm * 4 + mt;
                #pragma unroll
                for (int nt = 0; nt < 4; ++nt) {
                    int co = co0 + wn * 64 + nt * 16 + col;
                    float bv = bias[co];
                    f32x4 vv;
                    #pragma unroll
                    for (int r2 = 0; r2 < 4; ++r2) {
                        float z = acc[mt][nt][r2] + bv;
                        vv[r2] = z > 0.f ? z : 0.f;
                    }
                    *(f32x4*)&outp[((size_t)(b * COUT + co) * H + y) * W + x0 + quad * 4] = vv;
                }
            }
        }
    }
}

// ---------------------------------------------------------------------------
extern "C" void kernel_launch(void* const* d_in, const int* in_sizes, int n_in,
                              void* d_out, int out_size, void* d_ws, size_t ws_size,
                              hipStream_t stream)
{
    const float* x    = (const float*)d_in[0];
    const int*   mask = (const int*)d_in[1];
    const float* Wt[10];
    const float* bs[10];
    for (int i = 0; i < 10; ++i) {
        Wt[i] = (const float*)d_in[2 + 2 * i];
        bs[i] = (const float*)d_in[3 + 2 * i];
    }

    const size_t ACT = (size_t)4 * 384 * 384 * 64;   // ushorts
    ushort* A  = (ushort*)d_ws;
    ushort* Bb = A + ACT;
    ushort* wpbase = Bb + ACT;

    static const int cins[10]  = {3, 64, 64, 128, 128, 256, 256, 256, 512, 512};
    static const int couts[10] = {64, 64, 128, 128, 256, 256, 256, 512, 512, 512};
    ushort* wp[10];
    size_t wo = 0;
    for (int l = 1; l < 10; ++l) {
        wp[l] = wpbase + wo;
        wo += (size_t)couts[l] * cins[l] * 9;
    }
    int* counters = (int*)(wpbase + ((wo + 1) & ~(size_t)1));   // 4B-aligned

    for (int l = 1; l < 10; ++l) {
        int n = couts[l] * cins[l] * 9;
        repack_w<<<(n + 255) / 256, 256, 0, stream>>>(Wt[l], wp[l], cins[l], couts[l]);
    }
    zero_counters<<<1, 16, 0, stream>>>(counters);

    // L1: fp32 NCHW -> bf16 NHWC
    l1_conv<<<dim3(24 * 24, 1, 4), 256, 0, stream>>>(x, Wt[0], bs[0], A);

    // L2: 64->64 @384 (tile 16x16, BN=64)
    conv_mfma<16, 64, 64, 64, 384, 384, false, false>
        <<<dim3(2304), 256, 0, stream>>>(A, wp[1], bs[1], Bb, nullptr, counters + 0);
    maxpool_nhwc<<<(4 * 192 * 192 * 8 + 255) / 256, 256, 0, stream>>>(Bb, A, 192, 192, 64);

    // L3: 64->128 @192 (tile 8x16, BN=128)
    conv_mfma<8, 128, 64, 128, 192, 192, false, false>
        <<<dim3(1152), 256, 0, stream>>>(A, wp[2], bs[2], Bb, nullptr, counters + 1);
    // L4: 128->128 @192
    conv_mfma<8, 128, 128, 128, 192, 192, false, false>
        <<<dim3(1152), 256, 0, stream>>>(Bb, wp[3], bs[3], A, nullptr, counters + 2);
    maxpool_nhwc<<<(4 * 96 * 96 * 16 + 255) / 256, 256, 0, stream>>>(A, Bb, 96, 96, 128);

    // L5: 128->256 @96
    conv_mfma<8, 128, 128, 256, 96, 96, false, false>
        <<<dim3(576), 256, 0, stream>>>(Bb, wp[4], bs[4], A, nullptr, counters + 3);
    // L6: 256->256
    conv_mfma<8, 128, 256, 256, 96, 96, false, false>
        <<<dim3(576), 256, 0, stream>>>(A, wp[5], bs[5], Bb, nullptr, counters + 4);
    // L7: 256->256
    conv_mfma<8, 128, 256, 256, 96, 96, false, false>
        <<<dim3(576), 256, 0, stream>>>(Bb, wp[6], bs[6], A, nullptr, counters + 5);

    // irregular pool
    irpool_nhwc<<<(4 * 96 * 96 * 32 + 255) / 256, 256, 0, stream>>>(A, mask, Bb);

    // L8: gconv 256->512
    conv_mfma<8, 128, 256, 512, 96, 96, true, false>
        <<<dim3(1152), 256, 0, stream>>>(Bb, wp[7], bs[7], A, mask, counters + 6);
    // L9: gconv 512->512
    conv_mfma<8, 128, 512, 512, 96, 96, true, false>
        <<<dim3(1152), 256, 0, stream>>>(A, wp[8], bs[8], Bb, mask, counters + 7);
    // L10: gconv 512->512 -> fp32 NCHW d_out
    conv_mfma<8, 128, 512, 512, 96, 96, true, true>
        <<<dim3(1152), 256, 0, stream>>>(Bb, wp[9], bs[9], d_out, mask, counters + 8);

    (void)in_sizes; (void)n_in; (void)out_size; (void)ws_size;
}

// Round 5
// 899.660 us; speedup vs baseline: 1.2387x; 1.1304x over previous
//
#include <hip/hip_runtime.h>

// ---------------------------------------------------------------------------
// Round 10: R7 loop (best measured: 957us) + epilogue-fused pooling + merged
// repack. R9 post-mortem: persistent blocks helped L10 by ~4% but regressed
// the net 60us -> reverted. R8: B-from-global regressed -> LDS-resident B
// kept. Conflicts (1.302e7) are sA's data-dependent gconv gather: accepted.
// New here (all OFF the K-loop critical path):
//   - maxpool2 fused into L2/L4 epilogues (2x2 windows are thread-local:
//     mt-pairs x r2-pairs), irpool fused into L7 epilogue. Removes 3 kernels
//     and ~190 MB of HBM round-trips.
//   - 9 repack_w dispatches merged into 1 (repack_all).
// Dispatches: 23 -> 11.
// ---------------------------------------------------------------------------

typedef __attribute__((ext_vector_type(8))) short short8;
typedef __attribute__((ext_vector_type(4))) float f32x4;

__device__ __forceinline__ float b2f(ushort u) {
    return __uint_as_float(((unsigned)u) << 16);
}
__device__ __forceinline__ ushort f2b(float f) {   // round-to-nearest-even
    unsigned x = __float_as_uint(f);
    x += 0x7FFFu + ((x >> 16) & 1u);
    return (ushort)(x >> 16);
}
__device__ __forceinline__ ushort bmax(ushort a, ushort b) {
    return b2f(a) > b2f(b) ? a : b;
}
__device__ __forceinline__ float fmaxf2(float a, float b) { return a > b ? a : b; }

// ---- repack weights [co][ci][t] f32 -> [t][cb][q][co][ci8] bf16, all layers
struct RepackArgs {
    const float* w[9];
    ushort*      wp[9];
    int cin[9];
    int cout[9];
    int off[10];        // elem-count prefix sums, off[9] = total
};

__global__ __launch_bounds__(256)
void repack_all(RepackArgs a)
{
    int i = blockIdx.x * 256 + threadIdx.x;
    if (i >= a.off[9]) return;
    int l = 0;
    #pragma unroll
    for (int k = 1; k < 9; ++k) l += (i >= a.off[k]);
    int j = i - a.off[l];
    int Cin = a.cin[l], Cout = a.cout[l];
    int CBl  = Cin / 32;
    int c8   = j & 7;
    int co   = (j >> 3) % Cout;          // Cout is a power of two
    int rest = (j >> 3) / Cout;          // = (t*CBl + cb)*4 + q
    int q    = rest & 3;
    int cbt  = rest >> 2;
    int cb   = cbt % CBl;
    int t    = cbt / CBl;
    int ci   = cb * 32 + q * 8 + c8;
    a.wp[l][j] = f2b(a.w[l][((size_t)co * Cin + ci) * 9 + t]);
}

// ------------- L1: 3->64 direct conv, fp32 NCHW in -> bf16 NHWC out ---------
__global__ __launch_bounds__(256)
void l1_conv(const float* __restrict__ in, const float* __restrict__ w,
             const float* __restrict__ bias, ushort* __restrict__ out)
{
    const int H = 384, W = 384;
    __shared__ float s[3][18][18];
    const int tid = threadIdx.x;
    const int tilesX = W / 16;
    const int x0 = (blockIdx.x % tilesX) * 16;
    const int y0 = (blockIdx.x / tilesX) * 16;
    const int b  = blockIdx.z;

    for (int i = tid; i < 3 * 18 * 18; i += 256) {
        int ci = i / (18 * 18);
        int r  = i % (18 * 18);
        int iy = r / 18, ix = r % 18;
        int gy = y0 - 1 + iy, gx = x0 - 1 + ix;
        float v = 0.f;
        if ((unsigned)gy < (unsigned)H && (unsigned)gx < (unsigned)W)
            v = in[((size_t)(b * 3 + ci) * H + gy) * W + gx];
        s[ci][iy][ix] = v;
    }
    __syncthreads();

    const int tx = tid & 15, ty = tid >> 4;
    float iv[3][3][3];
    #pragma unroll
    for (int ci = 0; ci < 3; ++ci)
        #pragma unroll
        for (int ky = 0; ky < 3; ++ky)
            #pragma unroll
            for (int kx = 0; kx < 3; ++kx)
                iv[ci][ky][kx] = s[ci][ty + ky][tx + kx];

    size_t pix = ((size_t)(b * H + y0 + ty) * W + x0 + tx);
    #pragma unroll
    for (int c4 = 0; c4 < 4; ++c4) {
        __align__(16) ushort ob[16];
        #pragma unroll
        for (int co = 0; co < 16; ++co) {
            int coG = c4 * 16 + co;
            float a = bias[coG];
            #pragma unroll
            for (int ci = 0; ci < 3; ++ci)
                #pragma unroll
                for (int ky = 0; ky < 3; ++ky)
                    #pragma unroll
                    for (int kx = 0; kx < 3; ++kx)
                        a = fmaf(w[((size_t)coG * 3 + ci) * 9 + ky * 3 + kx],
                                 iv[ci][ky][kx], a);
            a = a > 0.f ? a : 0.f;
            ob[co] = f2b(a);
        }
        *(short8*)&out[pix * 64 + c4 * 16]     = *(short8*)&ob[0];
        *(short8*)&out[pix * 64 + c4 * 16 + 8] = *(short8*)&ob[8];
    }
}

// ------------- implicit-GEMM conv3x3, tap-row staged, bf16 MFMA -------------
// Block = TRx16 output pixels, 256 threads = 4 waves, wave tile 64x64.
// Per cb: A halo staged once; B staged per tap-ROW with register prefetch of
// next row's B / next cb's A before the MFMA section. Conflict-free LDS
// layouts (sA q-plane-major stride NCH+2; sB [tap][q][co] wave-linear).
// POOL: 0=none, 1=fused 2x2 maxpool (halved output), 2=fused irregular pool.
template<int TR, int BN, int CIN, int COUT, int H, int W, bool GCONV, bool FINAL,
         int POOL>
__global__ __launch_bounds__(256)
void conv_mfma(const ushort* __restrict__ in, const ushort* __restrict__ wp,
               const float* __restrict__ bias, void* __restrict__ outv,
               const int* __restrict__ mask)
{
    constexpr int BM   = TR * 16;
    constexpr int CB   = CIN / 32;
    constexpr int HA   = GCONV ? 2 : 1;
    constexpr int CW   = 16 + 2 * HA;
    constexpr int CR   = TR + 2 * HA;
    constexpr int NCH  = CR * CW;            // A chunks (pixels) per cb
    constexpr int NCHP = NCH + 2;            // q-plane stride (de-alias stores)
    constexpr int WM   = BM / 64;
    constexpr int NSA  = NCH * 4;            // 16B units to stage for A
    constexpr int NSLA = (NSA + 255) / 256;
    constexpr int NSB  = 12 * BN;            // 16B units per tap-row of B
    constexpr int NSLB = NSB / 256;
    static_assert(NSB % 256 == 0, "B staging must tile 256 threads");

    __shared__ __align__(16) ushort sA[4 * NCHP * 8];
    __shared__ __align__(16) ushort sB[12 * BN * 8];

    const int tid  = threadIdx.x;
    const int lane = tid & 63;
    const int wv   = tid >> 6;
    const int wm   = wv % WM;
    const int wn   = wv / WM;
    const int col  = lane & 15;
    const int quad = lane >> 4;

    const int tiles_x = W / 16, tiles_y = H / TR;
    int sp = blockIdx.x;
    const int b  = sp / (tiles_x * tiles_y);
    int rr = sp - b * tiles_x * tiles_y;
    const int ty = rr / tiles_x;
    const int tx = rr - ty * tiles_x;
    const int y0 = ty * TR, x0 = tx * 16;
    const int co0 = blockIdx.y * BN;

    int dA[4], aoff[4];
    #pragma unroll
    for (int mt = 0; mt < 4; ++mt) {
        dA[mt] = 1;
        if (GCONV) {
            int y = y0 + wm * 4 + mt, x = x0 + col;
            dA[mt] = mask[(b * (H / 2) + (y >> 1)) * (W / 2) + (x >> 1)] ? 2 : 1;
        }
        aoff[mt] = (HA + wm * 4 + mt) * CW + HA + col;
    }

    short8 pA[NSLA];
    short8 pB[NSLB];

    auto loadA = [&](int cb) {
        #pragma unroll
        for (int k = 0; k < NSLA; ++k) {
            int i = tid + k * 256;
            short8 v = {0, 0, 0, 0, 0, 0, 0, 0};
            if (NSA == NSLA * 256 || i < NSA) {
                int chunk = i >> 2, part = i & 3;     // coalesced: 64B / 4 lanes
                int yy = chunk / CW, xx = chunk - yy * CW;
                int gy = y0 - HA + yy, gx = x0 - HA + xx;
                if ((unsigned)gy < (unsigned)H && (unsigned)gx < (unsigned)W)
                    v = *(const short8*)(in + ((size_t)(b * H + gy) * W + gx) * CIN
                                         + cb * 32 + part * 8);
            }
            pA[k] = v;
        }
    };
    auto storeA = [&]() {
        #pragma unroll
        for (int k = 0; k < NSLA; ++k) {
            int i = tid + k * 256;
            if (NSA == NSLA * 256 || i < NSA) {
                int chunk = i >> 2, part = i & 3;
                *(short8*)&sA[(part * NCHP + chunk) * 8] = pA[k];
            }
        }
    };
    auto loadB = [&](int s) {
        int cb = s / 3, row = s % 3;
        #pragma unroll
        for (int k = 0; k < NSLB; ++k) {
            int i = tid + k * 256;
            int co = i % BN;
            int rq = i / BN;                     // tl*4 + q
            const ushort* gp = wp
                + (((size_t)(row * 3 + (rq >> 2)) * CB + cb) * 4 + (rq & 3))
                      * COUT * 8
                + (size_t)(co0 + co) * 8;
            pB[k] = *(const short8*)gp;          // wave reads 1KB contiguous
        }
    };
    auto storeB = [&]() {
        #pragma unroll
        for (int k = 0; k < NSLB; ++k) {
            int i = tid + k * 256;
            *(short8*)&sB[(size_t)i * 8] = pB[k];    // wave-linear, 0 conflicts
        }
    };

    f32x4 acc[4][4];
    #pragma unroll
    for (int i = 0; i < 4; ++i)
        #pragma unroll
        for (int j = 0; j < 4; ++j)
            acc[i][j] = (f32x4){0.f, 0.f, 0.f, 0.f};

    // prologue
    loadA(0);
    loadB(0);
    storeA();
    storeB();
    __syncthreads();

    for (int s = 0; s < 3 * CB; ++s) {
        const int row  = s % 3;
        const bool last = (s == 3 * CB - 1);
        if (!last) {
            loadB(s + 1);                 // global prefetch, lands at storeB
            if (row == 2) loadA(s / 3 + 1);
        }
        const int ky = row - 1;
        #pragma unroll
        for (int j = 0; j < 3; ++j) {
            const int kx = j - 1;
            short8 af[4], bf4[4];
            #pragma unroll
            for (int i = 0; i < 4; ++i) {
                int chunk = aoff[i] + dA[i] * (ky * CW + kx);
                af[i]  = *(const short8*)&sA[(quad * NCHP + chunk) * 8];
                bf4[i] = *(const short8*)&sB[((j * 4 + quad) * BN
                                              + wn * 64 + i * 16 + col) * 8];
            }
            #pragma unroll
            for (int mt = 0; mt < 4; ++mt)
                #pragma unroll
                for (int nt = 0; nt < 4; ++nt)
                    acc[mt][nt] = __builtin_amdgcn_mfma_f32_16x16x32_bf16(
                        af[mt], bf4[nt], acc[mt][nt], 0, 0, 0);
        }
        if (!last) {
            __syncthreads();              // all reads of sA/sB done
            storeB();
            if (row == 2) storeA();
            __syncthreads();              // writes visible
        }
    }

    // ---- epilogue ----
    if (FINAL) {
        float* outp = (float*)outv;   // fp32 NCHW direct to d_out
        #pragma unroll
        for (int mt = 0; mt < 4; ++mt) {
            int y = y0 + wm * 4 + mt;
            #pragma unroll
            for (int nt = 0; nt < 4; ++nt) {
                int co = co0 + wn * 64 + nt * 16 + col;
                float bv = bias[co];
                f32x4 vv;
                #pragma unroll
                for (int r2 = 0; r2 < 4; ++r2) {
                    float z = acc[mt][nt][r2] + bv;
                    vv[r2] = z > 0.f ? z : 0.f;
                }
                *(f32x4*)&outp[((size_t)(b * COUT + co) * H + y) * W + x0 + quad * 4] = vv;
            }
        }
    } else if (POOL == 0) {
        ushort* outp = (ushort*)outv;
        #pragma unroll
        for (int mt = 0; mt < 4; ++mt) {
            int y = y0 + wm * 4 + mt;
            #pragma unroll
            for (int nt = 0; nt < 4; ++nt) {
                int co = co0 + wn * 64 + nt * 16 + col;
                float bv = bias[co];
                #pragma unroll
                for (int r2 = 0; r2 < 4; ++r2) {
                    int x = x0 + quad * 4 + r2;
                    float vv = acc[mt][nt][r2] + bv;
                    vv = vv > 0.f ? vv : 0.f;
                    outp[((size_t)(b * H + y) * W + x) * COUT + co] = f2b(vv);
                }
            }
        }
    } else if (POOL == 1) {
        // fused 2x2 maxpool: output is (H/2)x(W/2), NHWC bf16.
        // 2x2 windows are thread-local: rows (wm*4+2*mt2, +1), cols (quad*4+2j, +1).
        ushort* outp = (ushort*)outv;
        #pragma unroll
        for (int nt = 0; nt < 4; ++nt) {
            int co = co0 + wn * 64 + nt * 16 + col;
            float bv = bias[co];
            float v[4][4];
            #pragma unroll
            for (int mt = 0; mt < 4; ++mt)
                #pragma unroll
                for (int r2 = 0; r2 < 4; ++r2) {
                    float z = acc[mt][nt][r2] + bv;
                    v[mt][r2] = z > 0.f ? z : 0.f;
                }
            #pragma unroll
            for (int mt2 = 0; mt2 < 2; ++mt2) {
                int yp = (y0 >> 1) + wm * 2 + mt2;
                #pragma unroll
                for (int j = 0; j < 2; ++j) {
                    int xp = (x0 >> 1) + quad * 2 + j;
                    float m = fmaxf2(fmaxf2(v[2*mt2][2*j],   v[2*mt2][2*j+1]),
                                     fmaxf2(v[2*mt2+1][2*j], v[2*mt2+1][2*j+1]));
                    outp[((size_t)(b * (H/2) + yp) * (W/2) + xp) * COUT + co] = f2b(m);
                }
            }
        }
    } else {
        // POOL == 2: fused irregular pool (mask-gated 2x2 max, replicated).
        ushort* outp = (ushort*)outv;
        int mc[2][2];
        #pragma unroll
        for (int my = 0; my < 2; ++my)
            #pragma unroll
            for (int mx = 0; mx < 2; ++mx) {
                int y = y0 + wm * 4 + my * 2;
                int x = x0 + quad * 4 + mx * 2;
                mc[my][mx] = mask[(b * (H / 2) + (y >> 1)) * (W / 2) + (x >> 1)];
            }
        #pragma unroll
        for (int nt = 0; nt < 4; ++nt) {
            int co = co0 + wn * 64 + nt * 16 + col;
            float bv = bias[co];
            float v[4][4];
            #pragma unroll
            for (int mt = 0; mt < 4; ++mt)
                #pragma unroll
                for (int r2 = 0; r2 < 4; ++r2) {
                    float z = acc[mt][nt][r2] + bv;
                    v[mt][r2] = z > 0.f ? z : 0.f;
                }
            #pragma unroll
            for (int mt = 0; mt < 4; ++mt) {
                int y = y0 + wm * 4 + mt;
                #pragma unroll
                for (int r2 = 0; r2 < 4; ++r2) {
                    int x = x0 + quad * 4 + r2;
                    float p = fmaxf2(fmaxf2(v[mt][r2],     v[mt][r2 ^ 1]),
                                     fmaxf2(v[mt ^ 1][r2], v[mt ^ 1][r2 ^ 1]));
                    float o = mc[mt >> 1][r2 >> 1] ? p : v[mt][r2];
                    outp[((size_t)(b * H + y) * W + x) * COUT + co] = f2b(o);
                }
            }
        }
    }
}

// ---------------------------------------------------------------------------
extern "C" void kernel_launch(void* const* d_in, const int* in_sizes, int n_in,
                              void* d_out, int out_size, void* d_ws, size_t ws_size,
                              hipStream_t stream)
{
    const float* x    = (const float*)d_in[0];
    const int*   mask = (const int*)d_in[1];
    const float* Wt[10];
    const float* bs[10];
    for (int i = 0; i < 10; ++i) {
        Wt[i] = (const float*)d_in[2 + 2 * i];
        bs[i] = (const float*)d_in[3 + 2 * i];
    }

    const size_t ACT = (size_t)4 * 384 * 384 * 64;   // ushorts
    ushort* A  = (ushort*)d_ws;
    ushort* Bb = A + ACT;
    ushort* wpbase = Bb + ACT;

    static const int cins[10]  = {3, 64, 64, 128, 128, 256, 256, 256, 512, 512};
    static const int couts[10] = {64, 64, 128, 128, 256, 256, 256, 512, 512, 512};
    ushort* wp[10];
    size_t wo = 0;
    for (int l = 1; l < 10; ++l) {
        wp[l] = wpbase + wo;
        wo += (size_t)couts[l] * cins[l] * 9;
    }

    RepackArgs ra;
    int off = 0;
    for (int l = 1; l < 10; ++l) {
        ra.w[l - 1]    = Wt[l];
        ra.wp[l - 1]   = wp[l];
        ra.cin[l - 1]  = cins[l];
        ra.cout[l - 1] = couts[l];
        ra.off[l - 1]  = off;
        off += couts[l] * cins[l] * 9;
    }
    ra.off[9] = off;
    repack_all<<<(off + 255) / 256, 256, 0, stream>>>(ra);

    // L1: fp32 NCHW -> bf16 NHWC
    l1_conv<<<dim3(24 * 24, 1, 4), 256, 0, stream>>>(x, Wt[0], bs[0], A);

    // L2: 64->64 @384 (tile 16x16, BN=64), fused maxpool -> 192^2
    conv_mfma<16, 64, 64, 64, 384, 384, false, false, 1>
        <<<dim3(4 * 24 * 24, 1), 256, 0, stream>>>(A, wp[1], bs[1], Bb, nullptr);

    // L3: 64->128 @192 (tile 8x16, BN=128)
    conv_mfma<8, 128, 64, 128, 192, 192, false, false, 0>
        <<<dim3(4 * 24 * 12, 1), 256, 0, stream>>>(Bb, wp[2], bs[2], A, nullptr);
    // L4: 128->128 @192, fused maxpool -> 96^2
    conv_mfma<8, 128, 128, 128, 192, 192, false, false, 1>
        <<<dim3(4 * 24 * 12, 1), 256, 0, stream>>>(A, wp[3], bs[3], Bb, nullptr);

    // L5: 128->256 @96
    conv_mfma<8, 128, 128, 256, 96, 96, false, false, 0>
        <<<dim3(4 * 12 * 6, 2), 256, 0, stream>>>(Bb, wp[4], bs[4], A, nullptr);
    // L6: 256->256
    conv_mfma<8, 128, 256, 256, 96, 96, false, false, 0>
        <<<dim3(4 * 12 * 6, 2), 256, 0, stream>>>(A, wp[5], bs[5], Bb, nullptr);
    // L7: 256->256, fused irregular pool
    conv_mfma<8, 128, 256, 256, 96, 96, false, false, 2>
        <<<dim3(4 * 12 * 6, 2), 256, 0, stream>>>(Bb, wp[6], bs[6], A, mask);

    // L8: gconv 256->512
    conv_mfma<8, 128, 256, 512, 96, 96, true, false, 0>
        <<<dim3(4 * 12 * 6, 4), 256, 0, stream>>>(A, wp[7], bs[7], Bb, mask);
    // L9: gconv 512->512
    conv_mfma<8, 128, 512, 512, 96, 96, true, false, 0>
        <<<dim3(4 * 12 * 6, 4), 256, 0, stream>>>(Bb, wp[8], bs[8], A, mask);
    // L10: gconv 512->512 -> fp32 NCHW d_out
    conv_mfma<8, 128, 512, 512, 96, 96, true, true, 0>
        <<<dim3(4 * 12 * 6, 4), 256, 0, stream>>>(A, wp[9], bs[9], d_out, mask);

    (void)in_sizes; (void)n_in; (void)out_size; (void)ws_size;
}